// Round 10
// baseline (866.756 us; speedup 1.0000x reference)
//
#include <hip/hip_runtime.h>
#include <math.h>

#define NN 20000
#define EE 320000
#define ETOT 340000
#define DEGCAP 128

typedef __attribute__((ext_vector_type(8))) short short8;
typedef __attribute__((ext_vector_type(4))) float f32x4;

__device__ __forceinline__ float lrelu(float x, float s) { return fmaxf(x, s * x); }
__device__ __forceinline__ float bf2f(ushort u) {
    union { uint i; float f; } c;
    c.i = ((uint)u) << 16;
    return c.f;
}
__device__ __forceinline__ ushort f2bf(float f) {
    uint u = __float_as_uint(f);
    uint r = (u + 0x7FFFu + ((u >> 16) & 1u)) >> 16;
    return (ushort)r;
}
__device__ __forceinline__ void gload16(const ushort* g, const ushort* l) {
    __builtin_amdgcn_global_load_lds((const __attribute__((address_space(1))) void*)g,
                                     (__attribute__((address_space(3))) void*)l, 16, 0, 0);
}

// ---------------- CSR build ----------------
__global__ __launch_bounds__(1024) void k_scan(const int* __restrict__ counts, int* __restrict__ rstart) {
    __shared__ int sm[1024];
    int t = threadIdx.x;
    const int CH = 20;
    int base = t * CH;
    int loc[CH];
    int s = 0;
#pragma unroll
    for (int j = 0; j < CH; ++j) {
        int idx = base + j;
        int v = (idx < NN) ? counts[idx] : 0;
        loc[j] = s;
        s += v;
    }
    sm[t] = s;
    __syncthreads();
    for (int o = 1; o < 1024; o <<= 1) {
        int v = (t >= o) ? sm[t - o] : 0;
        __syncthreads();
        if (t >= o) sm[t] += v;
        __syncthreads();
    }
    int off = sm[t] - s;
#pragma unroll
    for (int j = 0; j < CH; ++j) {
        int idx = base + j;
        if (idx < NN) rstart[idx] = off + loc[j];
    }
    if (t == 1023) rstart[NN] = sm[1023];
}

__global__ void k_scatter(const int* __restrict__ ei, const int* __restrict__ rstart,
                          int* __restrict__ cursor, int* __restrict__ csr) {
    int i = blockIdx.x * blockDim.x + threadIdx.x;
    if (i >= ETOT) return;
    int d = (i < EE) ? ei[EE + i] : (i - EE);
    int pos = atomicAdd(&cursor[d], 1);
    csr[rstart[d] + pos] = i;
}

// ---------------- merged prep: cast x, cast 6 weights, count degrees ----------------
__global__ void k_prep(const float* __restrict__ x, const float* __restrict__ w0, const float* __restrict__ w1,
                       const float* __restrict__ w2, const float* __restrict__ w3, const float* __restrict__ w4,
                       const float* __restrict__ w5, ushort* __restrict__ xout, ushort* __restrict__ wout,
                       const int* __restrict__ ei, int* __restrict__ counts) {
    int b = blockIdx.x, t = threadIdx.x;
    if (b < 10000) {
        int i = (b * 256 + t) * 4;
        float4 v = *(const float4*)(x + i);
        uint2 pk;
        pk.x = (uint)f2bf(v.x) | ((uint)f2bf(v.y) << 16);
        pk.y = (uint)f2bf(v.z) | ((uint)f2bf(v.w) << 16);
        *(uint2*)(xout + i) = pk;
    } else if (b < 11536) {
        int q = (b - 10000) * 256 + t;
        if (q >= 6 * 65536) return;
        int which = q >> 16;
        int off = (q & 65535) << 2;
        const float* src = which == 0 ? w0 : which == 1 ? w1 : which == 2 ? w2 : which == 3 ? w3 : which == 4 ? w4 : w5;
        float4 v = *(const float4*)(src + off);
        uint2 pk;
        pk.x = (uint)f2bf(v.x) | ((uint)f2bf(v.y) << 16);
        pk.y = (uint)f2bf(v.z) | ((uint)f2bf(v.w) << 16);
        *(uint2*)(wout + which * 262144 + off) = pk;
    } else {
        int i = (b - 11536) * 256 + t;
        if (i >= ETOT) return;
        int d = (i < EE) ? ei[EE + i] : (i - EE);
        atomicAdd(&counts[d], 1);
    }
}

// ---------------- merged MFMA GEMM: 8 waves, wave tile 64x32, BK=32, counted-vmcnt dbuf ----------------
// [xl|xr] = A[NN x 512] @ W[1024 x 512]^T + [bl|br]; 1256 blocks, XCD-swizzled n-fastest.
// Block 0 also zeroes bsum/bsq (1024 floats) for the downstream k_fused stats atomics.
__global__ __launch_bounds__(512, 4) void k_gemm2(const ushort* __restrict__ A, const ushort* __restrict__ W,
                                                  const float* __restrict__ bl, const float* __restrict__ br,
                                                  ushort* __restrict__ XL, ushort* __restrict__ XR,
                                                  float* __restrict__ bz) {
    __shared__ ushort As[2][4][128][8];  // [buf][kslot][row][8] : 2 x 8 KB
    __shared__ ushort Bs[2][4][128][8];
    int tid = threadIdx.x;
    int wid = tid >> 6, lane = tid & 63;
    int wm = wid >> 2, wn = wid & 3;  // 2 x 4 waves; wave tile 64 rows x 32 cols
    int bid = blockIdx.x;
    if (bid == 0) {
        float2 z = {0.f, 0.f};
        ((float2*)bz)[tid] = z;  // 512 threads x 8B = 1024 floats (bsum+bsq)
    }
    int L = (bid & 7) * 157 + (bid >> 3);  // bijective: 1256 % 8 == 0
    int mt = L >> 3, nt = L & 7;
    int bm = mt * 128, bn = nt * 128;
    const float* bias = (nt >= 4) ? br : bl;
    ushort* C = (nt >= 4) ? XR : XL;
    int cb = bn - ((nt >= 4) ? 512 : 0);
    int lrow = lane & 15, lslot = lane >> 4;
    int r = tid & 127, ks = tid >> 7;
    int ar = bm + r;
    if (ar >= NN) ar = NN - 1;  // clamp: rows >= NN computed but never stored
    const ushort* gA = A + (size_t)ar * 512 + ks * 8;
    const ushort* gB = W + (size_t)(bn + r) * 512 + ks * 8;
    const ushort* lA[2] = {&As[0][0][0][0] + (size_t)(wid * 64) * 8, &As[1][0][0][0] + (size_t)(wid * 64) * 8};
    const ushort* lB[2] = {&Bs[0][0][0][0] + (size_t)(wid * 64) * 8, &Bs[1][0][0][0] + (size_t)(wid * 64) * 8};
    f32x4 acc[4][2] = {};
    // prologue: tile 0 -> buf 0
    gload16(gA, lA[0]);
    gload16(gB, lB[0]);
#pragma unroll
    for (int t = 0; t < 16; ++t) {
        const int cur = t & 1;
        if (t < 15) {
            int k0 = (t + 1) * 32;
            gload16(gA + k0, lA[cur ^ 1]);
            gload16(gB + k0, lB[cur ^ 1]);
            asm volatile("s_waitcnt vmcnt(2)" ::: "memory");  // oldest 2 (= tile t) landed; prefetch in flight
        } else {
            asm volatile("s_waitcnt vmcnt(0)" ::: "memory");
        }
        __builtin_amdgcn_s_barrier();  // all threads' tile-t chunks resident
        short8 af[4], bfr[2];
#pragma unroll
        for (int i = 0; i < 4; ++i) af[i] = *(const short8*)&As[cur][lslot][wm * 64 + i * 16 + lrow][0];
#pragma unroll
        for (int j = 0; j < 2; ++j) bfr[j] = *(const short8*)&Bs[cur][lslot][wn * 32 + j * 16 + lrow][0];
#pragma unroll
        for (int i = 0; i < 4; ++i)
#pragma unroll
            for (int j = 0; j < 2; ++j)
                acc[i][j] = __builtin_amdgcn_mfma_f32_16x16x32_bf16(af[i], bfr[j], acc[i][j], 0, 0, 0);
        __builtin_amdgcn_s_barrier();  // reads of buf[cur] consumed
    }
#pragma unroll
    for (int i = 0; i < 4; ++i) {
#pragma unroll
        for (int j = 0; j < 2; ++j) {
            int gcol = cb + wn * 32 + j * 16 + lrow;
            float bv = bias[gcol];
            int growb = bm + wm * 64 + i * 16 + lslot * 4;
#pragma unroll
            for (int reg = 0; reg < 4; ++reg) {
                int grow = growb + reg;
                if (grow < NN) C[(size_t)grow * 512 + gcol] = f2bf(acc[i][j][reg] + bv);
            }
        }
    }
}

// ---------------- fused logits + online-softmax + aggregation + BN-stats ----------------
// One wave per dst node; epilogue accumulates per-column sum/sumsq into LDS then
// global-atomicAdds into bsum/bsq (zeroed by the preceding k_gemm2).
__global__ __launch_bounds__(256) void k_fused(const ushort* __restrict__ xl, const ushort* __restrict__ xr,
                                               const float* __restrict__ att, const int* __restrict__ ei,
                                               const int* __restrict__ rstart, const int* __restrict__ csr,
                                               const float* __restrict__ bias, float* __restrict__ alpha,
                                               ushort* __restrict__ dest, float* __restrict__ bstat,
                                               int meanHeads) {
    __shared__ float slg[4][DEGCAP][4];
    __shared__ int ssrc[4][DEGCAP];
    __shared__ float sstat[1024];  // [0,512): sum, [512,1024): sumsq
#pragma unroll
    for (int i = 0; i < 4; ++i) sstat[threadIdx.x + i * 256] = 0.f;
    __syncthreads();
    int w = threadIdx.x >> 6, lane = threadIdx.x & 63;
    int node = blockIdx.x * 4 + w;
    int s0 = rstart[node];
    int deg = rstart[node + 1] - s0;
    int hh = lane >> 4;
    short8 xrv = *(const short8*)(xr + (size_t)node * 512 + lane * 8);
    const float4* at = (const float4*)att + lane * 2;
    float4 a0 = at[0], a1 = at[1];
    float attv[8] = {a0.x, a0.y, a0.z, a0.w, a1.x, a1.y, a1.z, a1.w};
    float xrf[8];
#pragma unroll
    for (int j = 0; j < 8; ++j) xrf[j] = bf2f((ushort)xrv[j]);
    for (int i = lane; i < deg; i += 64) {
        int e = csr[s0 + i];
        ssrc[w][i < DEGCAP ? i : 0] = (e < EE) ? ei[e] : e - EE;
    }
    float m = -1e30f, denom = 0.f;
    float acc[8] = {};
    int scur = ssrc[w][0];
    short8 row = *(const short8*)(xl + (size_t)scur * 512 + lane * 8);
    for (int i = 0; i < deg; ++i) {
        short8 rown = row;
        if (i + 1 < deg) {
            int sn = ssrc[w][(i + 1) < DEGCAP ? (i + 1) : 0];
            rown = *(const short8*)(xl + (size_t)sn * 512 + lane * 8);
        }
        float rf[8];
#pragma unroll
        for (int j = 0; j < 8; ++j) rf[j] = bf2f((ushort)row[j]);
        float p = 0.f;
#pragma unroll
        for (int j = 0; j < 8; ++j) {
            float e = rf[j] + xrf[j];
            p = fmaf(fmaxf(e, 0.2f * e), attv[j], p);
        }
        p += __shfl_xor(p, 1);
        p += __shfl_xor(p, 2);
        p += __shfl_xor(p, 4);
        p += __shfl_xor(p, 8);
        if ((lane & 15) == 0 && i < DEGCAP) slg[w][i][hh] = p;
        if (p <= m) {
            float wg = __expf(p - m);
            denom += wg;
#pragma unroll
            for (int j = 0; j < 8; ++j) acc[j] = fmaf(wg, rf[j], acc[j]);
        } else {
            float sc = __expf(m - p);
            denom = fmaf(denom, sc, 1.f);
#pragma unroll
            for (int j = 0; j < 8; ++j) acc[j] = fmaf(acc[j], sc, rf[j]);
            m = p;
        }
        row = rown;
    }
    float rd = 1.f / denom;
    float m0 = __shfl(m, 0), m1 = __shfl(m, 16), m2 = __shfl(m, 32), m3 = __shfl(m, 48);
    float r0 = __shfl(rd, 0), r1 = __shfl(rd, 16), r2 = __shfl(rd, 32), r3 = __shfl(rd, 48);
    int nal = deg < DEGCAP ? deg : DEGCAP;
    for (int i = lane; i < nal; i += 64) {
        int e = csr[s0 + i];
        float4 l = *(const float4*)&slg[w][i][0];
        float4 av;
        av.x = __expf(l.x - m0) * r0;
        av.y = __expf(l.y - m1) * r1;
        av.z = __expf(l.z - m2) * r2;
        av.w = __expf(l.w - m3) * r3;
        *(float4*)(alpha + (size_t)e * 4) = av;
    }
#pragma unroll
    for (int j = 0; j < 8; ++j) acc[j] *= rd;
    if (!meanHeads) {
        int c = lane * 8;
        short8 o;
#pragma unroll
        for (int j = 0; j < 8; ++j) {
            float y = acc[j] + bias[c + j];
            o[j] = (short)f2bf(y);
            atomicAdd(&sstat[c + j], y);
            atomicAdd(&sstat[512 + c + j], y * y);
        }
        *(short8*)(dest + (size_t)node * 512 + c) = o;
    } else {
#pragma unroll
        for (int j = 0; j < 8; ++j) {
            acc[j] += __shfl_xor(acc[j], 16);
            acc[j] += __shfl_xor(acc[j], 32);
        }
        if (lane < 16) {
            int c = lane * 8;
            short8 o;
#pragma unroll
            for (int j = 0; j < 8; ++j) {
                float y = 0.25f * acc[j] + bias[c + j];
                o[j] = (short)f2bf(y);
                atomicAdd(&sstat[c + j], y);
                atomicAdd(&sstat[512 + c + j], y * y);
            }
            *(short8*)(dest + (size_t)node * 128 + c) = o;
        }
    }
    __syncthreads();
#pragma unroll
    for (int i = 0; i < 4; ++i) {
        int idx = threadIdx.x + i * 256;
        float v = sstat[idx];
        if (v != 0.f) atomicAdd(&bstat[idx], v);
    }
}

// ---------------- batch norm apply (bf16 input; mu/rs inline from bsum/bsq) ----------------
__global__ void k_bnapply(const ushort* __restrict__ X, const float* __restrict__ g, const float* __restrict__ b,
                          const float* __restrict__ bsum, const float* __restrict__ bsq, float* __restrict__ Yf,
                          ushort* __restrict__ Yb, float* __restrict__ gout, int mask4, int n4) {
    int i = blockIdx.x * blockDim.x + threadIdx.x;
    if (gout && i < NN) gout[i] = 1.0f;
    if (i >= n4) return;
    int c = (i & mask4) << 2;
    uint2 p = ((const uint2*)X)[i];
    float x0 = bf2f((ushort)(p.x & 0xffffu)), x1 = bf2f((ushort)(p.x >> 16));
    float x2 = bf2f((ushort)(p.y & 0xffffu)), x3 = bf2f((ushort)(p.y >> 16));
    float4 S = *(const float4*)(bsum + c);
    float4 Q = *(const float4*)(bsq + c);
    float4 G = *(const float4*)(g + c);
    float4 B = *(const float4*)(b + c);
    const float inv = 1.f / NN;
    float mx = S.x * inv, my = S.y * inv, mz = S.z * inv, mw = S.w * inv;
    float rx = rsqrtf(Q.x * inv - mx * mx + 1e-5f);
    float ry = rsqrtf(Q.y * inv - my * my + 1e-5f);
    float rz = rsqrtf(Q.z * inv - mz * mz + 1e-5f);
    float rw = rsqrtf(Q.w * inv - mw * mw + 1e-5f);
    float4 y;
    y.x = lrelu(G.x * (x0 - mx) * rx + B.x, 0.01f);
    y.y = lrelu(G.y * (x1 - my) * ry + B.y, 0.01f);
    y.z = lrelu(G.z * (x2 - mz) * rz + B.z, 0.01f);
    y.w = lrelu(G.w * (x3 - mw) * rw + B.w, 0.01f);
    if (Yb) {
        uint2 pk;
        pk.x = (uint)f2bf(y.x) | ((uint)f2bf(y.y) << 16);
        pk.y = (uint)f2bf(y.z) | ((uint)f2bf(y.w) << 16);
        *(uint2*)(Yb + (size_t)i * 4) = pk;
    } else {
        ((float4*)Yf)[i] = y;
    }
}

extern "C" void kernel_launch(void* const* d_in, const int* in_sizes, int n_in,
                              void* d_out, int out_size, void* d_ws, size_t ws_size,
                              hipStream_t stream) {
    const float* x = (const float*)d_in[0];
    const int* ei = (const int*)d_in[1];
    const float* wl[3] = {(const float*)d_in[3], (const float*)d_in[11], (const float*)d_in[19]};
    const float* bl[3] = {(const float*)d_in[4], (const float*)d_in[12], (const float*)d_in[20]};
    const float* wr[3] = {(const float*)d_in[5], (const float*)d_in[13], (const float*)d_in[21]};
    const float* br[3] = {(const float*)d_in[6], (const float*)d_in[14], (const float*)d_in[22]};
    const float* att[3] = {(const float*)d_in[7], (const float*)d_in[15], (const float*)d_in[23]};
    const float* bias[3] = {(const float*)d_in[8], (const float*)d_in[16], (const float*)d_in[24]};
    const float* bng[3] = {(const float*)d_in[9], (const float*)d_in[17], (const float*)d_in[25]};
    const float* bnb[3] = {(const float*)d_in[10], (const float*)d_in[18], (const float*)d_in[26]};

    // ---- workspace layout ----
    ushort* a_bf = (ushort*)d_ws;               // NN*512
    ushort* xl_bf = a_bf + (size_t)NN * 512;    // NN*512
    ushort* xr_bf = xl_bf + (size_t)NN * 512;   // NN*512
    ushort* h_bf = xr_bf + (size_t)NN * 512;    // NN*512 (pre-BN bf16)
    ushort* wbuf = h_bf + (size_t)NN * 512;     // 6*262144
    float* fp = (float*)(wbuf + 6 * 262144);
    float* bsum = fp;                           // 512  (bsq adjacent -> bstat[1024])
    float* bsq = bsum + 512;                    // 512
    int* counts = (int*)(bsq + 512);            // NN
    int* cursor = counts + NN;                  // NN
    int* rstart = cursor + NN;                  // NN+1
    int* csr = rstart + (NN + 1);               // ETOT
    size_t need = (size_t)((char*)(csr + ETOT) - (char*)d_ws);
    if (ws_size < need) return;

    float* out = (float*)d_out;
    float* zout = out;                                               // 20000 x 128
    float* aout[3] = {out + 2560000, out + 3920000, out + 5280000};  // 340000 x 4 each
    float* gout = out + 6640000;                                     // 20000

    // zero counts+cursor, then merged prep (casts + degree count), then scan/scatter
    hipMemsetAsync(counts, 0, 2 * NN * sizeof(int), stream);
    k_prep<<<12865, 256, 0, stream>>>(x, wl[0], wr[0], wl[1], wr[1], wl[2], wr[2], a_bf, wbuf, ei, counts);
    k_scan<<<1, 1024, 0, stream>>>(counts, rstart);
    k_scatter<<<(ETOT + 255) / 256, 256, 0, stream>>>(ei, rstart, cursor, csr);

    for (int l = 0; l < 3; ++l) {
        const ushort* wb = wbuf + (size_t)l * 524288;  // [Wl;Wr] rows
        k_gemm2<<<1256, 512, 0, stream>>>(a_bf, wb, bl[l], br[l], xl_bf, xr_bf, bsum);
        int ncols = (l == 2) ? 128 : 512;
        k_fused<<<NN / 4, 256, 0, stream>>>(xl_bf, xr_bf, att[l], ei, rstart, csr, bias[l], aout[l], h_bf,
                                            bsum, (l == 2) ? 1 : 0);
        int n4 = NN * ncols / 4;
        if (l < 2) {
            k_bnapply<<<(n4 + 255) / 256, 256, 0, stream>>>(h_bf, bng[l], bnb[l], bsum, bsq, nullptr, a_bf,
                                                            nullptr, ncols / 4 - 1, n4);
        } else {
            k_bnapply<<<(n4 + 255) / 256, 256, 0, stream>>>(h_bf, bng[l], bnb[l], bsum, bsq, zout, nullptr,
                                                            gout, ncols / 4 - 1, n4);
        }
    }
}

// Round 11
// 653.800 us; speedup vs baseline: 1.3257x; 1.3257x over previous
//
#include <hip/hip_runtime.h>
#include <math.h>

#define NN 20000
#define EE 320000
#define ETOT 340000
#define DEGCAP 128

typedef __attribute__((ext_vector_type(8))) short short8;
typedef __attribute__((ext_vector_type(4))) float f32x4;

__device__ __forceinline__ float lrelu(float x, float s) { return fmaxf(x, s * x); }
__device__ __forceinline__ float bf2f(ushort u) {
    union { uint i; float f; } c;
    c.i = ((uint)u) << 16;
    return c.f;
}
__device__ __forceinline__ ushort f2bf(float f) {
    uint u = __float_as_uint(f);
    uint r = (u + 0x7FFFu + ((u >> 16) & 1u)) >> 16;
    return (ushort)r;
}
__device__ __forceinline__ void gload16(const ushort* g, const ushort* l) {
    __builtin_amdgcn_global_load_lds((const __attribute__((address_space(1))) void*)g,
                                     (__attribute__((address_space(3))) void*)l, 16, 0, 0);
}

// ---------------- CSR build ----------------
__global__ __launch_bounds__(1024) void k_scan(const int* __restrict__ counts, int* __restrict__ rstart) {
    __shared__ int sm[1024];
    int t = threadIdx.x;
    const int CH = 20;
    int base = t * CH;
    int loc[CH];
    int s = 0;
#pragma unroll
    for (int j = 0; j < CH; ++j) {
        int idx = base + j;
        int v = (idx < NN) ? counts[idx] : 0;
        loc[j] = s;
        s += v;
    }
    sm[t] = s;
    __syncthreads();
    for (int o = 1; o < 1024; o <<= 1) {
        int v = (t >= o) ? sm[t - o] : 0;
        __syncthreads();
        if (t >= o) sm[t] += v;
        __syncthreads();
    }
    int off = sm[t] - s;
#pragma unroll
    for (int j = 0; j < CH; ++j) {
        int idx = base + j;
        if (idx < NN) rstart[idx] = off + loc[j];
    }
    if (t == 1023) rstart[NN] = sm[1023];
}

__global__ void k_scatter(const int* __restrict__ ei, const int* __restrict__ rstart,
                          int* __restrict__ cursor, int* __restrict__ csr) {
    int i = blockIdx.x * blockDim.x + threadIdx.x;
    if (i >= ETOT) return;
    int d = (i < EE) ? ei[EE + i] : (i - EE);
    int pos = atomicAdd(&cursor[d], 1);
    csr[rstart[d] + pos] = i;
}

// ---------------- merged prep: cast x, cast 6 weights, count degrees ----------------
__global__ void k_prep(const float* __restrict__ x, const float* __restrict__ w0, const float* __restrict__ w1,
                       const float* __restrict__ w2, const float* __restrict__ w3, const float* __restrict__ w4,
                       const float* __restrict__ w5, ushort* __restrict__ xout, ushort* __restrict__ wout,
                       const int* __restrict__ ei, int* __restrict__ counts) {
    int b = blockIdx.x, t = threadIdx.x;
    if (b < 10000) {
        int i = (b * 256 + t) * 4;
        float4 v = *(const float4*)(x + i);
        uint2 pk;
        pk.x = (uint)f2bf(v.x) | ((uint)f2bf(v.y) << 16);
        pk.y = (uint)f2bf(v.z) | ((uint)f2bf(v.w) << 16);
        *(uint2*)(xout + i) = pk;
    } else if (b < 11536) {
        int q = (b - 10000) * 256 + t;
        if (q >= 6 * 65536) return;
        int which = q >> 16;
        int off = (q & 65535) << 2;
        const float* src = which == 0 ? w0 : which == 1 ? w1 : which == 2 ? w2 : which == 3 ? w3 : which == 4 ? w4 : w5;
        float4 v = *(const float4*)(src + off);
        uint2 pk;
        pk.x = (uint)f2bf(v.x) | ((uint)f2bf(v.y) << 16);
        pk.y = (uint)f2bf(v.z) | ((uint)f2bf(v.w) << 16);
        *(uint2*)(wout + which * 262144 + off) = pk;
    } else {
        int i = (b - 11536) * 256 + t;
        if (i >= ETOT) return;
        int d = (i < EE) ? ei[EE + i] : (i - EE);
        atomicAdd(&counts[d], 1);
    }
}

// ---------------- merged MFMA GEMM: 8 waves, wave tile 64x32, BK=32, counted-vmcnt dbuf ----------------
// [xl|xr] = A[NN x 512] @ W[1024 x 512]^T + [bl|br]; 1256 blocks, XCD-swizzled n-fastest.
// Block 0 also zeroes bsum/bsq (1024 floats) for the downstream k_bnstats atomics.
__global__ __launch_bounds__(512, 4) void k_gemm2(const ushort* __restrict__ A, const ushort* __restrict__ W,
                                                  const float* __restrict__ bl, const float* __restrict__ br,
                                                  ushort* __restrict__ XL, ushort* __restrict__ XR,
                                                  float* __restrict__ bz) {
    __shared__ ushort As[2][4][128][8];  // [buf][kslot][row][8] : 2 x 8 KB
    __shared__ ushort Bs[2][4][128][8];
    int tid = threadIdx.x;
    int wid = tid >> 6, lane = tid & 63;
    int wm = wid >> 2, wn = wid & 3;  // 2 x 4 waves; wave tile 64 rows x 32 cols
    int bid = blockIdx.x;
    if (bid == 0) {
        float2 z = {0.f, 0.f};
        ((float2*)bz)[tid] = z;  // 512 threads x 8B = 1024 floats (bsum+bsq)
    }
    int L = (bid & 7) * 157 + (bid >> 3);  // bijective: 1256 % 8 == 0
    int mt = L >> 3, nt = L & 7;
    int bm = mt * 128, bn = nt * 128;
    const float* bias = (nt >= 4) ? br : bl;
    ushort* C = (nt >= 4) ? XR : XL;
    int cb = bn - ((nt >= 4) ? 512 : 0);
    int lrow = lane & 15, lslot = lane >> 4;
    int r = tid & 127, ks = tid >> 7;
    int ar = bm + r;
    if (ar >= NN) ar = NN - 1;  // clamp: rows >= NN computed but never stored
    const ushort* gA = A + (size_t)ar * 512 + ks * 8;
    const ushort* gB = W + (size_t)(bn + r) * 512 + ks * 8;
    const ushort* lA[2] = {&As[0][0][0][0] + (size_t)(wid * 64) * 8, &As[1][0][0][0] + (size_t)(wid * 64) * 8};
    const ushort* lB[2] = {&Bs[0][0][0][0] + (size_t)(wid * 64) * 8, &Bs[1][0][0][0] + (size_t)(wid * 64) * 8};
    f32x4 acc[4][2] = {};
    // prologue: tile 0 -> buf 0
    gload16(gA, lA[0]);
    gload16(gB, lB[0]);
#pragma unroll
    for (int t = 0; t < 16; ++t) {
        const int cur = t & 1;
        if (t < 15) {
            int k0 = (t + 1) * 32;
            gload16(gA + k0, lA[cur ^ 1]);
            gload16(gB + k0, lB[cur ^ 1]);
            asm volatile("s_waitcnt vmcnt(2)" ::: "memory");  // oldest 2 (= tile t) landed; prefetch in flight
        } else {
            asm volatile("s_waitcnt vmcnt(0)" ::: "memory");
        }
        __builtin_amdgcn_s_barrier();  // all threads' tile-t chunks resident
        short8 af[4], bfr[2];
#pragma unroll
        for (int i = 0; i < 4; ++i) af[i] = *(const short8*)&As[cur][lslot][wm * 64 + i * 16 + lrow][0];
#pragma unroll
        for (int j = 0; j < 2; ++j) bfr[j] = *(const short8*)&Bs[cur][lslot][wn * 32 + j * 16 + lrow][0];
#pragma unroll
        for (int i = 0; i < 4; ++i)
#pragma unroll
            for (int j = 0; j < 2; ++j)
                acc[i][j] = __builtin_amdgcn_mfma_f32_16x16x32_bf16(af[i], bfr[j], acc[i][j], 0, 0, 0);
        __builtin_amdgcn_s_barrier();  // reads of buf[cur] consumed
    }
#pragma unroll
    for (int i = 0; i < 4; ++i) {
#pragma unroll
        for (int j = 0; j < 2; ++j) {
            int gcol = cb + wn * 32 + j * 16 + lrow;
            float bv = bias[gcol];
            int growb = bm + wm * 64 + i * 16 + lslot * 4;
#pragma unroll
            for (int reg = 0; reg < 4; ++reg) {
                int grow = growb + reg;
                if (grow < NN) C[(size_t)grow * 512 + gcol] = f2bf(acc[i][j][reg] + bv);
            }
        }
    }
}

// ---------------- fused logits + online-softmax + aggregation: one wave per dst node ----------------
__global__ __launch_bounds__(256) void k_fused(const ushort* __restrict__ xl, const ushort* __restrict__ xr,
                                               const float* __restrict__ att, const int* __restrict__ ei,
                                               const int* __restrict__ rstart, const int* __restrict__ csr,
                                               const float* __restrict__ bias, float* __restrict__ alpha,
                                               ushort* __restrict__ dest, int meanHeads) {
    __shared__ float slg[4][DEGCAP][4];
    __shared__ int ssrc[4][DEGCAP];
    int w = threadIdx.x >> 6, lane = threadIdx.x & 63;
    int node = blockIdx.x * 4 + w;
    int s0 = rstart[node];
    int deg = rstart[node + 1] - s0;
    int hh = lane >> 4;
    short8 xrv = *(const short8*)(xr + (size_t)node * 512 + lane * 8);
    const float4* at = (const float4*)att + lane * 2;
    float4 a0 = at[0], a1 = at[1];
    float attv[8] = {a0.x, a0.y, a0.z, a0.w, a1.x, a1.y, a1.z, a1.w};
    float xrf[8];
#pragma unroll
    for (int j = 0; j < 8; ++j) xrf[j] = bf2f((ushort)xrv[j]);
    for (int i = lane; i < deg; i += 64) {
        int e = csr[s0 + i];
        ssrc[w][i < DEGCAP ? i : 0] = (e < EE) ? ei[e] : e - EE;
    }
    float m = -1e30f, denom = 0.f;
    float acc[8] = {};
    int scur = ssrc[w][0];
    short8 row = *(const short8*)(xl + (size_t)scur * 512 + lane * 8);
    for (int i = 0; i < deg; ++i) {
        short8 rown = row;
        if (i + 1 < deg) {
            int sn = ssrc[w][(i + 1) < DEGCAP ? (i + 1) : 0];
            rown = *(const short8*)(xl + (size_t)sn * 512 + lane * 8);
        }
        float rf[8];
#pragma unroll
        for (int j = 0; j < 8; ++j) rf[j] = bf2f((ushort)row[j]);
        float p = 0.f;
#pragma unroll
        for (int j = 0; j < 8; ++j) {
            float e = rf[j] + xrf[j];
            p = fmaf(fmaxf(e, 0.2f * e), attv[j], p);
        }
        p += __shfl_xor(p, 1);
        p += __shfl_xor(p, 2);
        p += __shfl_xor(p, 4);
        p += __shfl_xor(p, 8);
        if ((lane & 15) == 0 && i < DEGCAP) slg[w][i][hh] = p;
        if (p <= m) {
            float wg = __expf(p - m);
            denom += wg;
#pragma unroll
            for (int j = 0; j < 8; ++j) acc[j] = fmaf(wg, rf[j], acc[j]);
        } else {
            float sc = __expf(m - p);
            denom = fmaf(denom, sc, 1.f);
#pragma unroll
            for (int j = 0; j < 8; ++j) acc[j] = fmaf(acc[j], sc, rf[j]);
            m = p;
        }
        row = rown;
    }
    float rd = 1.f / denom;
    float m0 = __shfl(m, 0), m1 = __shfl(m, 16), m2 = __shfl(m, 32), m3 = __shfl(m, 48);
    float r0 = __shfl(rd, 0), r1 = __shfl(rd, 16), r2 = __shfl(rd, 32), r3 = __shfl(rd, 48);
    int nal = deg < DEGCAP ? deg : DEGCAP;
    for (int i = lane; i < nal; i += 64) {
        int e = csr[s0 + i];
        float4 l = *(const float4*)&slg[w][i][0];
        float4 av;
        av.x = __expf(l.x - m0) * r0;
        av.y = __expf(l.y - m1) * r1;
        av.z = __expf(l.z - m2) * r2;
        av.w = __expf(l.w - m3) * r3;
        *(float4*)(alpha + (size_t)e * 4) = av;
    }
#pragma unroll
    for (int j = 0; j < 8; ++j) acc[j] *= rd;
    if (!meanHeads) {
        int c = lane * 8;
        short8 o;
#pragma unroll
        for (int j = 0; j < 8; ++j) o[j] = (short)f2bf(acc[j] + bias[c + j]);
        *(short8*)(dest + (size_t)node * 512 + c) = o;
    } else {
#pragma unroll
        for (int j = 0; j < 8; ++j) {
            acc[j] += __shfl_xor(acc[j], 16);
            acc[j] += __shfl_xor(acc[j], 32);
        }
        if (lane < 16) {
            int c = lane * 8;
            short8 o;
#pragma unroll
            for (int j = 0; j < 8; ++j) o[j] = (short)f2bf(0.25f * acc[j] + bias[c + j]);
            *(short8*)(dest + (size_t)node * 128 + c) = o;
        }
    }
}

// ---------------- batch norm stats (bf16 input; 240 blocks -> low atomic fan-in) ----------------
__global__ void k_bnstats(const ushort* __restrict__ X, float* __restrict__ s, float* __restrict__ s2, int npairs) {
    int t = threadIdx.x;
    if (t >= npairs) return;
    float a0 = 0.f, a1 = 0.f, q0 = 0.f, q1 = 0.f;
    for (int r = blockIdx.x; r < NN; r += gridDim.x) {
        uint p = ((const uint*)X)[r * npairs + t];
        float v0 = bf2f((ushort)(p & 0xffffu));
        float v1 = bf2f((ushort)(p >> 16));
        a0 += v0; q0 += v0 * v0;
        a1 += v1; q1 += v1 * v1;
    }
    atomicAdd(&s[2 * t], a0);
    atomicAdd(&s[2 * t + 1], a1);
    atomicAdd(&s2[2 * t], q0);
    atomicAdd(&s2[2 * t + 1], q1);
}

// ---------------- batch norm apply (bf16 input; mu/rs inline from bsum/bsq) ----------------
__global__ void k_bnapply(const ushort* __restrict__ X, const float* __restrict__ g, const float* __restrict__ b,
                          const float* __restrict__ bsum, const float* __restrict__ bsq, float* __restrict__ Yf,
                          ushort* __restrict__ Yb, float* __restrict__ gout, int mask4, int n4) {
    int i = blockIdx.x * blockDim.x + threadIdx.x;
    if (gout && i < NN) gout[i] = 1.0f;
    if (i >= n4) return;
    int c = (i & mask4) << 2;
    uint2 p = ((const uint2*)X)[i];
    float x0 = bf2f((ushort)(p.x & 0xffffu)), x1 = bf2f((ushort)(p.x >> 16));
    float x2 = bf2f((ushort)(p.y & 0xffffu)), x3 = bf2f((ushort)(p.y >> 16));
    float4 S = *(const float4*)(bsum + c);
    float4 Q = *(const float4*)(bsq + c);
    float4 G = *(const float4*)(g + c);
    float4 B = *(const float4*)(b + c);
    const float inv = 1.f / NN;
    float mx = S.x * inv, my = S.y * inv, mz = S.z * inv, mw = S.w * inv;
    float rx = rsqrtf(Q.x * inv - mx * mx + 1e-5f);
    float ry = rsqrtf(Q.y * inv - my * my + 1e-5f);
    float rz = rsqrtf(Q.z * inv - mz * mz + 1e-5f);
    float rw = rsqrtf(Q.w * inv - mw * mw + 1e-5f);
    float4 y;
    y.x = lrelu(G.x * (x0 - mx) * rx + B.x, 0.01f);
    y.y = lrelu(G.y * (x1 - my) * ry + B.y, 0.01f);
    y.z = lrelu(G.z * (x2 - mz) * rz + B.z, 0.01f);
    y.w = lrelu(G.w * (x3 - mw) * rw + B.w, 0.01f);
    if (Yb) {
        uint2 pk;
        pk.x = (uint)f2bf(y.x) | ((uint)f2bf(y.y) << 16);
        pk.y = (uint)f2bf(y.z) | ((uint)f2bf(y.w) << 16);
        *(uint2*)(Yb + (size_t)i * 4) = pk;
    } else {
        ((float4*)Yf)[i] = y;
    }
}

extern "C" void kernel_launch(void* const* d_in, const int* in_sizes, int n_in,
                              void* d_out, int out_size, void* d_ws, size_t ws_size,
                              hipStream_t stream) {
    const float* x = (const float*)d_in[0];
    const int* ei = (const int*)d_in[1];
    const float* wl[3] = {(const float*)d_in[3], (const float*)d_in[11], (const float*)d_in[19]};
    const float* bl[3] = {(const float*)d_in[4], (const float*)d_in[12], (const float*)d_in[20]};
    const float* wr[3] = {(const float*)d_in[5], (const float*)d_in[13], (const float*)d_in[21]};
    const float* br[3] = {(const float*)d_in[6], (const float*)d_in[14], (const float*)d_in[22]};
    const float* att[3] = {(const float*)d_in[7], (const float*)d_in[15], (const float*)d_in[23]};
    const float* bias[3] = {(const float*)d_in[8], (const float*)d_in[16], (const float*)d_in[24]};
    const float* bng[3] = {(const float*)d_in[9], (const float*)d_in[17], (const float*)d_in[25]};
    const float* bnb[3] = {(const float*)d_in[10], (const float*)d_in[18], (const float*)d_in[26]};

    // ---- workspace layout ----
    ushort* a_bf = (ushort*)d_ws;               // NN*512
    ushort* xl_bf = a_bf + (size_t)NN * 512;    // NN*512
    ushort* xr_bf = xl_bf + (size_t)NN * 512;   // NN*512
    ushort* h_bf = xr_bf + (size_t)NN * 512;    // NN*512 (pre-BN bf16)
    ushort* wbuf = h_bf + (size_t)NN * 512;     // 6*262144
    float* fp = (float*)(wbuf + 6 * 262144);
    float* bsum = fp;                           // 512  (bsq adjacent -> 1024-float zero region)
    float* bsq = bsum + 512;                    // 512
    int* counts = (int*)(bsq + 512);            // NN
    int* cursor = counts + NN;                  // NN
    int* rstart = cursor + NN;                  // NN+1
    int* csr = rstart + (NN + 1);               // ETOT
    size_t need = (size_t)((char*)(csr + ETOT) - (char*)d_ws);
    if (ws_size < need) return;

    float* out = (float*)d_out;
    float* zout = out;                                               // 20000 x 128
    float* aout[3] = {out + 2560000, out + 3920000, out + 5280000};  // 340000 x 4 each
    float* gout = out + 6640000;                                     // 20000

    // zero counts+cursor, then merged prep (casts + degree count), then scan/scatter
    hipMemsetAsync(counts, 0, 2 * NN * sizeof(int), stream);
    k_prep<<<12865, 256, 0, stream>>>(x, wl[0], wr[0], wl[1], wr[1], wl[2], wr[2], a_bf, wbuf, ei, counts);
    k_scan<<<1, 1024, 0, stream>>>(counts, rstart);
    k_scatter<<<(ETOT + 255) / 256, 256, 0, stream>>>(ei, rstart, cursor, csr);

    for (int l = 0; l < 3; ++l) {
        const ushort* wb = wbuf + (size_t)l * 524288;  // [Wl;Wr] rows
        k_gemm2<<<1256, 512, 0, stream>>>(a_bf, wb, bl[l], br[l], xl_bf, xr_bf, bsum);
        int ncols = (l == 2) ? 128 : 512;
        k_fused<<<NN / 4, 256, 0, stream>>>(xl_bf, xr_bf, att[l], ei, rstart, csr, bias[l], aout[l], h_bf,
                                            (l == 2) ? 1 : 0);
        k_bnstats<<<240, 256, 0, stream>>>(h_bf, bsum, bsq, ncols / 2);
        int n4 = NN * ncols / 4;
        if (l < 2) {
            k_bnapply<<<(n4 + 255) / 256, 256, 0, stream>>>(h_bf, bng[l], bnb[l], bsum, bsq, nullptr, a_bf,
                                                            nullptr, ncols / 4 - 1, n4);
        } else {
            k_bnapply<<<(n4 + 255) / 256, 256, 0, stream>>>(h_bf, bng[l], bnb[l], bsum, bsq, zout, nullptr,
                                                            gout, ncols / 4 - 1, n4);
        }
    }
}